// Round 19
// baseline (304.141 us; speedup 1.0000x reference)
//
#include <hip/hip_runtime.h>
#include <cmath>

typedef unsigned short u16;
typedef __bf16 bf16x8 __attribute__((ext_vector_type(8)));
typedef float f32x4 __attribute__((ext_vector_type(4)));
typedef unsigned short us8 __attribute__((ext_vector_type(8)));

#define MFMA16(a,b,c) __builtin_amdgcn_mfma_f32_16x16x32_bf16((a),(b),(c),0,0,0)

// ---------- helpers ----------
__device__ __forceinline__ u16 f2bf(float f){
  union { float f; unsigned u; } x; x.f = f;
  unsigned r = x.u + 0x7FFFu + ((x.u >> 16) & 1u);   // RTNE
  return (u16)(r >> 16);
}
__device__ __forceinline__ float bf2f(u16 v){
  union { unsigned u; float f; } x; x.u = ((unsigned)v) << 16; return x.f;
}
__device__ __forceinline__ void gload16(const void* g, void* l){
  __builtin_amdgcn_global_load_lds((const __attribute__((address_space(1))) void*)g,
                                   (__attribute__((address_space(3))) void*)l, 16, 0, 0);
}
__device__ __forceinline__ float block_sum256(float v, float* red, int tid){
  #pragma unroll
  for (int off = 32; off; off >>= 1) v += __shfl_xor(v, off);
  if ((tid & 63) == 0) red[tid >> 6] = v;
  __syncthreads();
  return red[0] + red[1] + red[2] + red[3];
}

// ---------- ALL fp32 -> bf16 converts in one launch ----------
__global__ __launch_bounds__(256) void k_convall(const float* __restrict__ s0,
                                                 const float* __restrict__ s1,
                                                 const float* __restrict__ s2,
                                                 const float* __restrict__ s3,
                                                 const float* __restrict__ s4,
                                                 const float* __restrict__ s5,
                                                 u16* __restrict__ d0, u16* __restrict__ d1,
                                                 u16* __restrict__ d2, u16* __restrict__ d3,
                                                 u16* __restrict__ d4, u16* __restrict__ d5){
  const int n0 = 4096 * 2048 / 4;                 // hidden
  const int n1 = 1536 * 2048 / 4;                 // wq_a
  const int n2 = 3072 * 1536 / 4;                 // wq_b (scaled)
  const int n3 = 4096 * 512 / 4;                  // wkv_b
  const int n4 = 2048 * 2048 / 4;                 // wo
  const int n5 = 640 * 2048 / 4;                  // wkv_a padded
  const int total = n0 + n1 + n2 + n3 + n4 + n5;
  const float SCL2 = 0.104117549f;                // 192^-0.5 * log2(e)
  int i = blockIdx.x * 256 + threadIdx.x;
  int stride = gridDim.x * 256;
  for (; i < total; i += stride){
    int j = i;
    if (j < n0){
      float4 v = reinterpret_cast<const float4*>(s0)[j];
      ushort4 o; o.x = f2bf(v.x); o.y = f2bf(v.y); o.z = f2bf(v.z); o.w = f2bf(v.w);
      reinterpret_cast<ushort4*>(d0)[j] = o;
    } else if ((j -= n0) < n1){
      float4 v = reinterpret_cast<const float4*>(s1)[j];
      ushort4 o; o.x = f2bf(v.x); o.y = f2bf(v.y); o.z = f2bf(v.z); o.w = f2bf(v.w);
      reinterpret_cast<ushort4*>(d1)[j] = o;
    } else if ((j -= n1) < n2){
      float4 v = reinterpret_cast<const float4*>(s2)[j];
      ushort4 o; o.x = f2bf(v.x * SCL2); o.y = f2bf(v.y * SCL2);
      o.z = f2bf(v.z * SCL2); o.w = f2bf(v.w * SCL2);
      reinterpret_cast<ushort4*>(d2)[j] = o;
    } else if ((j -= n2) < n3){
      float4 v = reinterpret_cast<const float4*>(s3)[j];
      ushort4 o; o.x = f2bf(v.x); o.y = f2bf(v.y); o.z = f2bf(v.z); o.w = f2bf(v.w);
      reinterpret_cast<ushort4*>(d3)[j] = o;
    } else if ((j -= n3) < n4){
      float4 v = reinterpret_cast<const float4*>(s4)[j];
      ushort4 o; o.x = f2bf(v.x); o.y = f2bf(v.y); o.z = f2bf(v.z); o.w = f2bf(v.w);
      reinterpret_cast<ushort4*>(d4)[j] = o;
    } else {
      j -= n4;
      int e = j * 4; int row = e >> 11; int col = e & 2047;
      ushort4 o;
      if (row < 576){
        float4 v = *reinterpret_cast<const float4*>(s5 + (size_t)row * 2048 + col);
        o.x = f2bf(v.x); o.y = f2bf(v.y); o.z = f2bf(v.z); o.w = f2bf(v.w);
      } else { o.x = 0; o.y = 0; o.z = 0; o.w = 0; }
      reinterpret_cast<ushort4*>(d5)[j] = o;
    }
  }
}

// ---------- GEMM: C[M,N] = A[M,K] * B[N,K]^T ----------
// 128x128 tile, BK=32, 4 waves; 2-phase prefetch double-buffer; XCD swizzle.
template<int OUT_BF16>
__global__ __launch_bounds__(256) void k_gemm(const u16* __restrict__ A,
                                              const u16* __restrict__ Bm,
                                              void* __restrict__ Cv,
                                              int M, int N, int K){
  __shared__ __align__(16) u16 sA[2][128 * 32];
  __shared__ __align__(16) u16 sB[2][128 * 32];
  const int tid = threadIdx.x, w = tid >> 6, l = tid & 63;
  const int ln = l & 15, lg = l >> 4;
  const int id  = blockIdx.x + gridDim.x * blockIdx.y;
  const int nwg = gridDim.x * gridDim.y;
  const int swz = (id & 7) * (nwg >> 3) + (id >> 3);
  const int bx  = swz & (gridDim.x - 1);          // gridDim.x = 32 (pow2)
  const int by  = swz / gridDim.x;
  const int m0 = bx * 128, n0 = by * 128;
  const int wr = w >> 1, wc = w & 1;
  const int trow = tid >> 2, tcol = (tid & 3) * 8;

  const f32x4 zf = {0.f, 0.f, 0.f, 0.f};
  f32x4 acc[4][4];
  #pragma unroll
  for (int i = 0; i < 4; ++i)
    #pragma unroll
    for (int j = 0; j < 4; ++j) acc[i][j] = zf;

  const u16* ga = A  + (size_t)(m0 + trow) * K + tcol;
  const u16* gb = Bm + (size_t)(n0 + trow) * K + tcol;
  const int nk = K >> 5;

  #define GSTAGE(kt_, bi_) {                                   \
    char* la_ = (char*)sA[bi_] + w * 1024;                     \
    char* lb_ = (char*)sB[bi_] + w * 1024;                     \
    gload16(ga + (kt_) * 32,                  la_);            \
    gload16(ga + (kt_) * 32 + (size_t)64 * K, la_ + 4096);     \
    gload16(gb + (kt_) * 32,                  lb_);            \
    gload16(gb + (kt_) * 32 + (size_t)64 * K, lb_ + 4096);     \
  }

  GSTAGE(0, 0);
  __syncthreads();

  for (int kt = 0; kt < nk; ++kt){
    const int bi = kt & 1;
    if (kt + 1 < nk) GSTAGE(kt + 1, bi ^ 1);    // prefetch under compute

    bf16x8 af[4], bfr[4];
    #pragma unroll
    for (int i = 0; i < 4; ++i)
      af[i] = *(const bf16x8*)&sA[bi][(wr * 64 + i * 16 + ln) * 32 + lg * 8];
    #pragma unroll
    for (int j = 0; j < 4; ++j)
      bfr[j] = *(const bf16x8*)&sB[bi][(wc * 64 + j * 16 + ln) * 32 + lg * 8];
    #pragma unroll
    for (int i = 0; i < 4; ++i)
      #pragma unroll
      for (int j = 0; j < 4; ++j)
        acc[i][j] = MFMA16(af[i], bfr[j], acc[i][j]);

    __syncthreads();   // drains prefetch vmcnt; buffer swap safe
  }
  #undef GSTAGE

  const int mb = m0 + wr * 64, nb = n0 + wc * 64;
  #pragma unroll
  for (int i = 0; i < 4; ++i)
    #pragma unroll
    for (int j = 0; j < 4; ++j)
      #pragma unroll
      for (int r = 0; r < 4; ++r){
        int mm = mb + i * 16 + lg * 4 + r;
        int nn = nb + j * 16 + ln;
        if (OUT_BF16) ((u16*)Cv)[(size_t)mm * N + nn] = f2bf(acc[i][j][r]);
        else          ((float*)Cv)[(size_t)mm * N + nn] = acc[i][j][r];
      }
}

// ---------- wkv_b GEMM (M4096,N4096,K512) with fused V-transpose ----------
__global__ __launch_bounds__(256) void k_gemm_kv(const u16* __restrict__ A,
                                                 const u16* __restrict__ Bm,
                                                 u16* __restrict__ C,
                                                 u16* __restrict__ Vt){
  __shared__ __align__(16) u16 lds[16384];     // 32 KB shared staging / bounce
  char* ldsc = (char*)lds;
  const int tid = threadIdx.x, w = tid >> 6, l = tid & 63;
  const int ln = l & 15, lg = l >> 4;
  const int id  = blockIdx.x + 32 * blockIdx.y;
  const int swz = (id & 7) * 128 + (id >> 3);   // nwg=1024
  const int bx  = swz & 31;
  const int by  = swz >> 5;
  const int m0 = bx * 128, n0 = by * 128;
  const int wr = w >> 1, wc = w & 1;
  const int trow = tid >> 2, tcol = (tid & 3) * 8;
  const int K = 512, N = 4096;

  const f32x4 zf = {0.f, 0.f, 0.f, 0.f};
  f32x4 acc[4][4];
  #pragma unroll
  for (int i = 0; i < 4; ++i)
    #pragma unroll
    for (int j = 0; j < 4; ++j) acc[i][j] = zf;

  const u16* ga = A  + (size_t)(m0 + trow) * K + tcol;
  const u16* gb = Bm + (size_t)(n0 + trow) * K + tcol;
  const int nk = K >> 5;                        // 16

  #define GKVSTAGE(kt_, bi_) {                                   \
    char* la_ = ldsc + (bi_) * 8192 + w * 1024;                  \
    char* lb_ = ldsc + 16384 + (bi_) * 8192 + w * 1024;          \
    gload16(ga + (kt_) * 32,                  la_);              \
    gload16(ga + (kt_) * 32 + (size_t)64 * K, la_ + 4096);       \
    gload16(gb + (kt_) * 32,                  lb_);              \
    gload16(gb + (kt_) * 32 + (size_t)64 * K, lb_ + 4096);       \
  }

  GKVSTAGE(0, 0);
  __syncthreads();

  for (int kt = 0; kt < nk; ++kt){
    const int bi = kt & 1;
    if (kt + 1 < nk) GKVSTAGE(kt + 1, bi ^ 1);  // prefetch under compute

    bf16x8 af[4], bfr[4];
    #pragma unroll
    for (int i = 0; i < 4; ++i)
      af[i] = *(const bf16x8*)(ldsc + bi * 8192 +
               (((wr * 64 + i * 16 + ln) * 32 + lg * 8) << 1));
    #pragma unroll
    for (int j = 0; j < 4; ++j)
      bfr[j] = *(const bf16x8*)(ldsc + 16384 + bi * 8192 +
               (((wc * 64 + j * 16 + ln) * 32 + lg * 8) << 1));
    #pragma unroll
    for (int i = 0; i < 4; ++i)
      #pragma unroll
      for (int j = 0; j < 4; ++j)
        acc[i][j] = MFMA16(af[i], bfr[j], acc[i][j]);

    __syncthreads();   // drains prefetch vmcnt; buffer swap safe
  }
  #undef GKVSTAGE

  if (!(by & 1)){
    const int mb = m0 + wr * 64, nb = n0 + wc * 64;
    #pragma unroll
    for (int i = 0; i < 4; ++i)
      #pragma unroll
      for (int j = 0; j < 4; ++j)
        #pragma unroll
        for (int r = 0; r < 4; ++r){
          int mm = mb + i * 16 + lg * 4 + r;
          int nn = nb + j * 16 + ln;
          C[(size_t)mm * N + nn] = f2bf(acc[i][j][r]);
        }
  } else {
    const int h = by >> 1;
    #pragma unroll
    for (int i = 0; i < 4; ++i)
      #pragma unroll
      for (int j = 0; j < 4; ++j){
        int nL = wc * 64 + j * 16 + ln;
        int mL = wr * 64 + i * 16 + lg * 4;
        union { u16 s[4]; unsigned long long u; } pk4;
        #pragma unroll
        for (int r = 0; r < 4; ++r) pk4.s[r] = f2bf(acc[i][j][r]);
        *(unsigned long long*)(ldsc + nL * 256 + ((mL * 2) ^ ((nL & 7) << 4))) = pk4.u;
      }
    __syncthreads();
    const int s0g = bx * 64;
    #pragma unroll
    for (int p = 0; p < 8; ++p){
      int idx = p * 256 + tid;
      int d = idx >> 4, mb8 = idx & 15;
      int m = mb8 * 8;
      us8 v = *(const us8*)(ldsc + d * 256 + ((m * 2) ^ ((d & 7) << 4)));
      union { u16 s[4]; unsigned long long u; } e0, e1;
      e0.s[0] = v[0]; e0.s[1] = v[2]; e0.s[2] = v[4]; e0.s[3] = v[6];
      e1.s[0] = v[1]; e1.s[1] = v[3]; e1.s[2] = v[5]; e1.s[3] = v[7];
      int sg = s0g + (m >> 1);
      *(unsigned long long*)(Vt + ((size_t)(h)      * 128 + d) * 2048 + sg) = e0.u;
      *(unsigned long long*)(Vt + ((size_t)(16 + h) * 128 + d) * 2048 + sg) = e1.u;
    }
  }
}

// ---------- fused RMSNorm, bf16 input (stride 2176) ----------
__global__ __launch_bounds__(256) void k_rms_fused(const u16* __restrict__ in,
                                                   const float* __restrict__ wq,
                                                   const float* __restrict__ wkv,
                                                   u16* __restrict__ outq,
                                                   u16* __restrict__ outkv,
                                                   u16* __restrict__ kpe,
                                                   float* __restrict__ cs_tab){
  __shared__ float red[4];
  const int row = blockIdx.x, tid = threadIdx.x;
  const u16* x = in + (size_t)row * 2176;
  float q8[8];
  const bool hasq = tid < 192;
  float ss = 0.f;
  if (hasq){
    us8 v = *(const us8*)(x + tid * 8);
    #pragma unroll
    for (int j = 0; j < 8; ++j){ q8[j] = bf2f(v[j]); ss += q8[j] * q8[j]; }
  }
  float tot = block_sum256(ss, red, tid);
  float inv = rsqrtf(tot * (1.f / 1536.f) + 1e-6f);
  if (hasq){
    union { u16 s[8]; us8 v; } o;
    #pragma unroll
    for (int j = 0; j < 8; ++j) o.s[j] = f2bf(q8[j] * inv * wq[tid * 8 + j]);
    *(us8*)(outq + (size_t)row * 1536 + tid * 8) = o.v;
  }
  __syncthreads();
  float k8[8];
  const bool haskv = tid < 64;
  float ss2 = 0.f;
  if (haskv){
    us8 v = *(const us8*)(x + 1536 + tid * 8);
    #pragma unroll
    for (int j = 0; j < 8; ++j){ k8[j] = bf2f(v[j]); ss2 += k8[j] * k8[j]; }
  }
  float tot2 = block_sum256(ss2, red, tid);
  float inv2 = rsqrtf(tot2 * (1.f / 512.f) + 1e-6f);
  if (haskv){
    union { u16 s[8]; us8 v; } o;
    #pragma unroll
    for (int j = 0; j < 8; ++j) o.s[j] = f2bf(k8[j] * inv2 * wkv[tid * 8 + j]);
    *(us8*)(outkv + (size_t)row * 512 + tid * 8) = o.v;
  }
  if (tid < 32){
    int j = tid;
    float e = bf2f(x[2048 + 2 * j]), o = bf2f(x[2048 + 2 * j + 1]);
    float pos  = (float)(row >> 1);
    float invf = exp2f(-13.287712379549449f * (float)j * (1.f / 32.f));
    float th = pos * invf, sn = sinf(th), cs = cosf(th);
    kpe[(size_t)row * 64 + j]      = f2bf(e * cs - o * sn);
    kpe[(size_t)row * 64 + 32 + j] = f2bf(o * cs + e * sn);
    cs_tab[(size_t)row * 64 + j]      = cs;
    cs_tab[(size_t)row * 64 + 32 + j] = sn;
  }
}

// ---------- flash attention, causal (R13 structure + T5 setprio) ----------
__global__ __launch_bounds__(256, 2) void k_attn(const u16* __restrict__ q,
                                                 const u16* __restrict__ kv,
                                                 const u16* __restrict__ kpe,
                                                 const u16* __restrict__ vt,
                                                 const float* __restrict__ cs_tab,
                                                 u16* __restrict__ out){
  const int i_ = blockIdx.x + 16 * (blockIdx.y + 16 * blockIdx.z);
  const int j_ = i_ >> 3, x_ = i_ & 7;
  const int g_ = x_ * 4 + (j_ >> 4);
  const int bx = j_ & 15;
  const int h = g_ & 15, b = g_ >> 4;
  const int bh = b * 16 + h;
  const int tid = threadIdx.x, w = tid >> 6, l = tid & 63;
  const int ln = l & 15, lg = l >> 4;

  __shared__ __align__(16) u16 sK[2][64 * 128];
  __shared__ __align__(16) u16 sPE[2][64 * 64];
  __shared__ __align__(16) u16 sV[2][128 * 64];

  const f32x4 zf = {0.f, 0.f, 0.f, 0.f};

  #define PERM(pr_) ((((pr_) >> 5) << 5) + ((((pr_) >> 2) & 3) << 3) + \
                     ((((pr_) >> 4) & 1) << 2) + ((pr_) & 3))
  #define STAGE(kt_, bi_) {                                                     \
    _Pragma("unroll")                                                           \
    for (int p = 0; p < 4; ++p){                                                \
      int o_ = p * 4096 + tid * 16;                                             \
      int pr = o_ >> 8, cl = (o_ >> 4) & 15, cg = cl ^ (pr & 7);                \
      int kl = PERM(pr);                                                        \
      gload16(kv + (size_t)(((kt_) * 64 + kl) * 2 + b) * 4096 + h * 256 + cg * 8, \
              (char*)sK[bi_] + o_);                                             \
    }                                                                           \
    _Pragma("unroll")                                                           \
    for (int p = 0; p < 2; ++p){                                                \
      int o_ = p * 4096 + tid * 16;                                             \
      int pr = o_ >> 7, cl = (o_ >> 4) & 7, cg = cl ^ (pr & 7);                 \
      int kl = PERM(pr);                                                        \
      gload16(kpe + (size_t)(((kt_) * 64 + kl) * 2 + b) * 64 + cg * 8,          \
              (char*)sPE[bi_] + o_);                                            \
    }                                                                           \
    _Pragma("unroll")                                                           \
    for (int p = 0; p < 4; ++p){                                                \
      int o_ = p * 4096 + tid * 16;                                             \
      int row = o_ >> 7, cl = (o_ >> 4) & 7, cg = cl ^ (row & 7);               \
      gload16(vt + (size_t)(bh * 128 + row) * 2048 + (kt_) * 64 + cg * 8,       \
              (char*)sV[bi_] + o_);                                             \
    } }

  for (int half = 0; half < 2; ++half){
    const int qt = half ? (31 - bx) : bx;
    const int qrow0 = qt * 64 + w * 16;
    const int sq = qrow0 + ln;

    bf16x8 qf[6];
    {
      const u16* qr = q + (size_t)(sq * 2 + b) * 3072 + h * 192;
      #pragma unroll
      for (int kb = 0; kb < 4; ++kb) qf[kb] = *(const bf16x8*)(qr + kb * 32 + lg * 8);
      u16 rawa[16];
      *(us8*)&rawa[0] = *(const us8*)(qr + 128 + 16 * lg);
      *(us8*)&rawa[8] = *(const us8*)(qr + 128 + 16 * lg + 8);
      const float* ct = cs_tab + (size_t)(sq * 2 + b) * 64 + 8 * lg;
      float cc[8], ss_[8];
      *(float4*)&cc[0]  = *(const float4*)(ct);
      *(float4*)&cc[4]  = *(const float4*)(ct + 4);
      *(float4*)&ss_[0] = *(const float4*)(ct + 32);
      *(float4*)&ss_[4] = *(const float4*)(ct + 36);
      union { u16 s[8]; bf16x8 v; } pe4, pe5;
      #pragma unroll
      for (int i2 = 0; i2 < 8; ++i2){
        float e  = bf2f(rawa[2 * i2]);
        float o2 = bf2f(rawa[2 * i2 + 1]);
        pe4.s[i2] = f2bf(e * cc[i2] - o2 * ss_[i2]);
        pe5.s[i2] = f2bf(o2 * cc[i2] + e * ss_[i2]);
      }
      qf[4] = pe4.v;
      qf[5] = pe5.v;
    }

    f32x4 o[8];
    float m_i = -3.0e38f, l_i = 0.f;
    #pragma unroll
    for (int c8 = 0; c8 < 8; ++c8) o[c8] = zf;

    const int nkt = qt + 1;
    STAGE(0, 0);
    __syncthreads();

    for (int kt = 0; kt < nkt; ++kt){
      const int bi = kt & 1;
      if (kt + 1 < nkt) STAGE(kt + 1, bi ^ 1);

      f32x4 s_[4];
      __builtin_amdgcn_s_setprio(1);            // T5: favor MFMA cluster
      #pragma unroll
      for (int cb = 0; cb < 4; ++cb){
        int rl = cb * 16 + ln, swz = rl & 7;
        bf16x8 kf[6];
        #pragma unroll
        for (int kb = 0; kb < 4; ++kb)
          kf[kb] = *(const bf16x8*)((char*)sK[bi] + rl * 256 + (((kb * 4 + lg) ^ swz) << 4));
        kf[4] = *(const bf16x8*)((char*)sPE[bi] + rl * 128 + ((lg ^ swz) << 4));
        kf[5] = *(const bf16x8*)((char*)sPE[bi] + rl * 128 + (((4 + lg) ^ swz) << 4));
        f32x4 acc = zf;
        #pragma unroll
        for (int kb = 0; kb < 6; ++kb)
          acc = MFMA16(kf[kb], qf[kb], acc);
        s_[cb] = acc;
      }
      __builtin_amdgcn_s_setprio(0);

      const bool needMask = (kt * 64 + 63) > qrow0;
      float mx = -3.0e38f;
      #pragma unroll
      for (int cb = 0; cb < 4; ++cb)
        #pragma unroll
        for (int r = 0; r < 4; ++r){
          float v = s_[cb][r];
          if (needMask){
            int sk = kt * 64 + 32 * (cb >> 1) + 8 * lg + 4 * (cb & 1) + r;
            v = (sk <= sq) ? v : -3.0e38f;
          }
          s_[cb][r] = v;
          mx = fmaxf(mx, v);
        }
      mx = fmaxf(mx, __shfl_xor(mx, 16));
      mx = fmaxf(mx, __shfl_xor(mx, 32));
      if (!__all(mx <= m_i + 11.6f)){
        float mn = fmaxf(m_i, mx);
        float sf = exp2f(m_i - mn);
        m_i = mn;
        l_i *= sf;
        float sf0 = __shfl(sf, 4 * lg + 0);
        float sf1 = __shfl(sf, 4 * lg + 1);
        float sf2 = __shfl(sf, 4 * lg + 2);
        float sf3 = __shfl(sf, 4 * lg + 3);
        #pragma unroll
        for (int c8 = 0; c8 < 8; ++c8){
          o[c8][0] *= sf0; o[c8][1] *= sf1; o[c8][2] *= sf2; o[c8][3] *= sf3;
        }
      }
      float rs = 0.f;
      #pragma unroll
      for (int cb = 0; cb < 4; ++cb)
        #pragma unroll
        for (int r = 0; r < 4; ++r){
          float p = exp2f(s_[cb][r] - m_i);
          s_[cb][r] = p;
          rs += p;
        }
      rs += __shfl_xor(rs, 16);
      rs += __shfl_xor(rs, 32);
      l_i += rs;

      bf16x8 pa[2];
      #pragma unroll
      for (int hf = 0; hf < 2; ++hf){
        unsigned pw0, pw1, pw2, pw3;
        f32x4 sa = s_[hf * 2], sb2 = s_[hf * 2 + 1];
        asm("v_cvt_pk_bf16_f32 %0, %1, %2" : "=v"(pw0) : "v"(sa[0]),  "v"(sa[1]));
        asm("v_cvt_pk_bf16_f32 %0, %1, %2" : "=v"(pw1) : "v"(sa[2]),  "v"(sa[3]));
        asm("v_cvt_pk_bf16_f32 %0, %1, %2" : "=v"(pw2) : "v"(sb2[0]), "v"(sb2[1]));
        asm("v_cvt_pk_bf16_f32 %0, %1, %2" : "=v"(pw3) : "v"(sb2[2]), "v"(sb2[3]));
        union { uint4 u; bf16x8 v; } pk;
        pk.u.x = pw0; pk.u.y = pw1; pk.u.z = pw2; pk.u.w = pw3;
        pa[hf] = pk.v;
      }

      __builtin_amdgcn_s_setprio(1);            // T5: favor PV MFMA cluster
      #pragma unroll
      for (int c8 = 0; c8 < 8; ++c8){
        int d = c8 * 16 + ln, swz = d & 7;
        bf16x8 vf0 = *(const bf16x8*)((char*)sV[bi] + d * 128 + ((lg ^ swz) << 4));
        bf16x8 vf1 = *(const bf16x8*)((char*)sV[bi] + d * 128 + (((4 + lg) ^ swz) << 4));
        o[c8] = MFMA16(pa[0], vf0, o[c8]);
        o[c8] = MFMA16(pa[1], vf1, o[c8]);
      }
      __builtin_amdgcn_s_setprio(0);
      __syncthreads();
    }

    float li0 = __shfl(l_i, 4 * lg + 0);
    float li1 = __shfl(l_i, 4 * lg + 1);
    float li2 = __shfl(l_i, 4 * lg + 2);
    float li3 = __shfl(l_i, 4 * lg + 3);
    float iv0 = 1.f / li0, iv1 = 1.f / li1, iv2 = 1.f / li2, iv3 = 1.f / li3;
    int sqr = qrow0 + lg * 4;
    #pragma unroll
    for (int c8 = 0; c8 < 8; ++c8){
      int col = h * 128 + c8 * 16 + ln;
      out[(size_t)((sqr + 0) * 2 + b) * 2048 + col] = f2bf(o[c8][0] * iv0);
      out[(size_t)((sqr + 1) * 2 + b) * 2048 + col] = f2bf(o[c8][1] * iv1);
      out[(size_t)((sqr + 2) * 2 + b) * 2048 + col] = f2bf(o[c8][2] * iv2);
      out[(size_t)((sqr + 3) * 2 + b) * 2048 + col] = f2bf(o[c8][3] * iv3);
    }
  }
  #undef STAGE
  #undef PERM
}

// ---------- launch ----------
extern "C" void kernel_launch(void* const* d_in, const int* in_sizes, int n_in,
                              void* d_out, int out_size, void* d_ws, size_t ws_size,
                              hipStream_t stream){
  const float* hidden    = (const float*)d_in[0];
  const float* wq_a      = (const float*)d_in[3];
  const float* q_a_ln_w  = (const float*)d_in[4];
  const float* wq_b      = (const float*)d_in[5];
  const float* wkv_a     = (const float*)d_in[6];
  const float* kv_a_ln_w = (const float*)d_in[7];
  const float* wkv_b     = (const float*)d_in[8];
  const float* wo        = (const float*)d_in[9];

  char* ws = (char*)d_ws;
  size_t off = 0;
  auto alloc = [&](size_t bytes){ size_t o = off; off += (bytes + 255) & ~(size_t)255; return o; };
  const size_t SB = 4096;

  u16*   hid_bf   = (u16*)(ws + alloc(SB * 2048 * 2));
  u16*   wqab_bf  = (u16*)(ws + alloc((size_t)2176 * 2048 * 2));
  u16*   wqb_bf   = (u16*)(ws + alloc((size_t)3072 * 1536 * 2));
  u16*   wkvb_bf  = (u16*)(ws + alloc((size_t)4096 * 512 * 2));
  u16*   wo_bf    = (u16*)(ws + alloc((size_t)2048 * 2048 * 2));
  u16*   qa_bf    = (u16*)(ws + alloc(SB * 2176 * 2));   // merged q_a | ckv (bf16)
  u16*   qrms_bf  = (u16*)(ws + alloc(SB * 1536 * 2));
  u16*   ckvr_bf  = (u16*)(ws + alloc(SB * 512 * 2));
  u16*   kpe_bf   = (u16*)(ws + alloc(SB * 64 * 2));
  float* cs_f     = (float*)(ws + alloc(SB * 64 * 4));
  u16*   qfull_bf = (u16*)(ws + alloc(SB * 3072 * 2));
  u16*   kv_bf    = (u16*)(ws + alloc(SB * 4096 * 2));
  u16*   attn_bf  = (u16*)(ws + alloc(SB * 2048 * 2));
  u16*   vt_bf    = hid_bf;        // alias: hidden_bf16 dead after merged GEMM1

  dim3 blk(256);
  k_convall<<<2048, blk, 0, stream>>>(hidden, wq_a, wq_b, wkv_b, wo, wkv_a,
                                      hid_bf, wqab_bf, wqb_bf, wkvb_bf, wo_bf,
                                      wqab_bf + (size_t)1536 * 2048);
  k_gemm<1><<<dim3(32, 17), blk, 0, stream>>>(hid_bf, wqab_bf, qa_bf, 4096, 2176, 2048);
  k_rms_fused<<<4096, blk, 0, stream>>>(qa_bf, q_a_ln_w, kv_a_ln_w, qrms_bf, ckvr_bf,
                                        kpe_bf, cs_f);
  k_gemm<1><<<dim3(32, 24), blk, 0, stream>>>(qrms_bf, wqb_bf, qfull_bf, 4096, 3072, 1536);
  k_gemm_kv<<<dim3(32, 32), blk, 0, stream>>>(ckvr_bf, wkvb_bf, kv_bf, vt_bf);
  k_attn<<<dim3(16, 16, 2), blk, 0, stream>>>(qfull_bf, kv_bf, kpe_bf, vt_bf, cs_f, attn_bf);
  k_gemm<0><<<dim3(32, 16), blk, 0, stream>>>(attn_bf, wo_bf, d_out, 4096, 2048, 2048);
}

// Round 20
// 300.660 us; speedup vs baseline: 1.0116x; 1.0116x over previous
//
#include <hip/hip_runtime.h>
#include <cmath>

typedef unsigned short u16;
typedef __bf16 bf16x8 __attribute__((ext_vector_type(8)));
typedef float f32x4 __attribute__((ext_vector_type(4)));
typedef unsigned short us8 __attribute__((ext_vector_type(8)));

#define MFMA16(a,b,c) __builtin_amdgcn_mfma_f32_16x16x32_bf16((a),(b),(c),0,0,0)

// ---------- helpers ----------
__device__ __forceinline__ u16 f2bf(float f){
  union { float f; unsigned u; } x; x.f = f;
  unsigned r = x.u + 0x7FFFu + ((x.u >> 16) & 1u);   // RTNE
  return (u16)(r >> 16);
}
__device__ __forceinline__ float bf2f(u16 v){
  union { unsigned u; float f; } x; x.u = ((unsigned)v) << 16; return x.f;
}
__device__ __forceinline__ void gload16(const void* g, void* l){
  __builtin_amdgcn_global_load_lds((const __attribute__((address_space(1))) void*)g,
                                   (__attribute__((address_space(3))) void*)l, 16, 0, 0);
}
__device__ __forceinline__ float block_sum256(float v, float* red, int tid){
  #pragma unroll
  for (int off = 32; off; off >>= 1) v += __shfl_xor(v, off);
  if ((tid & 63) == 0) red[tid >> 6] = v;
  __syncthreads();
  return red[0] + red[1] + red[2] + red[3];
}

// ---------- ALL fp32 -> bf16 converts in one launch ----------
__global__ __launch_bounds__(256) void k_convall(const float* __restrict__ s0,
                                                 const float* __restrict__ s1,
                                                 const float* __restrict__ s2,
                                                 const float* __restrict__ s3,
                                                 const float* __restrict__ s4,
                                                 const float* __restrict__ s5,
                                                 u16* __restrict__ d0, u16* __restrict__ d1,
                                                 u16* __restrict__ d2, u16* __restrict__ d3,
                                                 u16* __restrict__ d4, u16* __restrict__ d5){
  const int n0 = 4096 * 2048 / 4;                 // hidden
  const int n1 = 1536 * 2048 / 4;                 // wq_a
  const int n2 = 3072 * 1536 / 4;                 // wq_b (scaled)
  const int n3 = 4096 * 512 / 4;                  // wkv_b
  const int n4 = 2048 * 2048 / 4;                 // wo
  const int n5 = 640 * 2048 / 4;                  // wkv_a padded
  const int total = n0 + n1 + n2 + n3 + n4 + n5;
  const float SCL2 = 0.104117549f;                // 192^-0.5 * log2(e)
  int i = blockIdx.x * 256 + threadIdx.x;
  int stride = gridDim.x * 256;
  for (; i < total; i += stride){
    int j = i;
    if (j < n0){
      float4 v = reinterpret_cast<const float4*>(s0)[j];
      ushort4 o; o.x = f2bf(v.x); o.y = f2bf(v.y); o.z = f2bf(v.z); o.w = f2bf(v.w);
      reinterpret_cast<ushort4*>(d0)[j] = o;
    } else if ((j -= n0) < n1){
      float4 v = reinterpret_cast<const float4*>(s1)[j];
      ushort4 o; o.x = f2bf(v.x); o.y = f2bf(v.y); o.z = f2bf(v.z); o.w = f2bf(v.w);
      reinterpret_cast<ushort4*>(d1)[j] = o;
    } else if ((j -= n1) < n2){
      float4 v = reinterpret_cast<const float4*>(s2)[j];
      ushort4 o; o.x = f2bf(v.x * SCL2); o.y = f2bf(v.y * SCL2);
      o.z = f2bf(v.z * SCL2); o.w = f2bf(v.w * SCL2);
      reinterpret_cast<ushort4*>(d2)[j] = o;
    } else if ((j -= n2) < n3){
      float4 v = reinterpret_cast<const float4*>(s3)[j];
      ushort4 o; o.x = f2bf(v.x); o.y = f2bf(v.y); o.z = f2bf(v.z); o.w = f2bf(v.w);
      reinterpret_cast<ushort4*>(d3)[j] = o;
    } else if ((j -= n3) < n4){
      float4 v = reinterpret_cast<const float4*>(s4)[j];
      ushort4 o; o.x = f2bf(v.x); o.y = f2bf(v.y); o.z = f2bf(v.z); o.w = f2bf(v.w);
      reinterpret_cast<ushort4*>(d4)[j] = o;
    } else {
      j -= n4;
      int e = j * 4; int row = e >> 11; int col = e & 2047;
      ushort4 o;
      if (row < 576){
        float4 v = *reinterpret_cast<const float4*>(s5 + (size_t)row * 2048 + col);
        o.x = f2bf(v.x); o.y = f2bf(v.y); o.z = f2bf(v.z); o.w = f2bf(v.w);
      } else { o.x = 0; o.y = 0; o.z = 0; o.w = 0; }
      reinterpret_cast<ushort4*>(d5)[j] = o;
    }
  }
}

// ---------- GEMM: C[M,N] = A[M,K] * B[N,K]^T ----------
// 128x128 tile, BK=32, 4 waves; 2-phase prefetch double-buffer; XCD swizzle.
template<int OUT_BF16>
__global__ __launch_bounds__(256) void k_gemm(const u16* __restrict__ A,
                                              const u16* __restrict__ Bm,
                                              void* __restrict__ Cv,
                                              int M, int N, int K){
  __shared__ __align__(16) u16 sA[2][128 * 32];
  __shared__ __align__(16) u16 sB[2][128 * 32];
  const int tid = threadIdx.x, w = tid >> 6, l = tid & 63;
  const int ln = l & 15, lg = l >> 4;
  const int id  = blockIdx.x + gridDim.x * blockIdx.y;
  const int nwg = gridDim.x * gridDim.y;
  const int swz = (id & 7) * (nwg >> 3) + (id >> 3);
  const int bx  = swz & (gridDim.x - 1);          // gridDim.x = 32 (pow2)
  const int by  = swz / gridDim.x;
  const int m0 = bx * 128, n0 = by * 128;
  const int wr = w >> 1, wc = w & 1;
  const int trow = tid >> 2, tcol = (tid & 3) * 8;

  const f32x4 zf = {0.f, 0.f, 0.f, 0.f};
  f32x4 acc[4][4];
  #pragma unroll
  for (int i = 0; i < 4; ++i)
    #pragma unroll
    for (int j = 0; j < 4; ++j) acc[i][j] = zf;

  const u16* ga = A  + (size_t)(m0 + trow) * K + tcol;
  const u16* gb = Bm + (size_t)(n0 + trow) * K + tcol;
  const int nk = K >> 5;

  #define GSTAGE(kt_, bi_) {                                   \
    char* la_ = (char*)sA[bi_] + w * 1024;                     \
    char* lb_ = (char*)sB[bi_] + w * 1024;                     \
    gload16(ga + (kt_) * 32,                  la_);            \
    gload16(ga + (kt_) * 32 + (size_t)64 * K, la_ + 4096);     \
    gload16(gb + (kt_) * 32,                  lb_);            \
    gload16(gb + (kt_) * 32 + (size_t)64 * K, lb_ + 4096);     \
  }

  GSTAGE(0, 0);
  __syncthreads();

  for (int kt = 0; kt < nk; ++kt){
    const int bi = kt & 1;
    if (kt + 1 < nk) GSTAGE(kt + 1, bi ^ 1);    // prefetch under compute

    bf16x8 af[4], bfr[4];
    #pragma unroll
    for (int i = 0; i < 4; ++i)
      af[i] = *(const bf16x8*)&sA[bi][(wr * 64 + i * 16 + ln) * 32 + lg * 8];
    #pragma unroll
    for (int j = 0; j < 4; ++j)
      bfr[j] = *(const bf16x8*)&sB[bi][(wc * 64 + j * 16 + ln) * 32 + lg * 8];
    #pragma unroll
    for (int i = 0; i < 4; ++i)
      #pragma unroll
      for (int j = 0; j < 4; ++j)
        acc[i][j] = MFMA16(af[i], bfr[j], acc[i][j]);

    __syncthreads();   // drains prefetch vmcnt; buffer swap safe
  }
  #undef GSTAGE

  const int mb = m0 + wr * 64, nb = n0 + wc * 64;
  #pragma unroll
  for (int i = 0; i < 4; ++i)
    #pragma unroll
    for (int j = 0; j < 4; ++j)
      #pragma unroll
      for (int r = 0; r < 4; ++r){
        int mm = mb + i * 16 + lg * 4 + r;
        int nn = nb + j * 16 + ln;
        if (OUT_BF16) ((u16*)Cv)[(size_t)mm * N + nn] = f2bf(acc[i][j][r]);
        else          ((float*)Cv)[(size_t)mm * N + nn] = acc[i][j][r];
      }
}

// ---------- wkv_b GEMM (M4096,N4096,K512) with fused V-transpose ----------
__global__ __launch_bounds__(256) void k_gemm_kv(const u16* __restrict__ A,
                                                 const u16* __restrict__ Bm,
                                                 u16* __restrict__ C,
                                                 u16* __restrict__ Vt){
  __shared__ __align__(16) u16 lds[16384];     // 32 KB shared staging / bounce
  char* ldsc = (char*)lds;
  const int tid = threadIdx.x, w = tid >> 6, l = tid & 63;
  const int ln = l & 15, lg = l >> 4;
  const int id  = blockIdx.x + 32 * blockIdx.y;
  const int swz = (id & 7) * 128 + (id >> 3);   // nwg=1024
  const int bx  = swz & 31;
  const int by  = swz >> 5;
  const int m0 = bx * 128, n0 = by * 128;
  const int wr = w >> 1, wc = w & 1;
  const int trow = tid >> 2, tcol = (tid & 3) * 8;
  const int K = 512, N = 4096;

  const f32x4 zf = {0.f, 0.f, 0.f, 0.f};
  f32x4 acc[4][4];
  #pragma unroll
  for (int i = 0; i < 4; ++i)
    #pragma unroll
    for (int j = 0; j < 4; ++j) acc[i][j] = zf;

  const u16* ga = A  + (size_t)(m0 + trow) * K + tcol;
  const u16* gb = Bm + (size_t)(n0 + trow) * K + tcol;
  const int nk = K >> 5;                        // 16

  #define GKVSTAGE(kt_, bi_) {                                   \
    char* la_ = ldsc + (bi_) * 8192 + w * 1024;                  \
    char* lb_ = ldsc + 16384 + (bi_) * 8192 + w * 1024;          \
    gload16(ga + (kt_) * 32,                  la_);              \
    gload16(ga + (kt_) * 32 + (size_t)64 * K, la_ + 4096);       \
    gload16(gb + (kt_) * 32,                  lb_);              \
    gload16(gb + (kt_) * 32 + (size_t)64 * K, lb_ + 4096);       \
  }

  GKVSTAGE(0, 0);
  __syncthreads();

  for (int kt = 0; kt < nk; ++kt){
    const int bi = kt & 1;
    if (kt + 1 < nk) GKVSTAGE(kt + 1, bi ^ 1);  // prefetch under compute

    bf16x8 af[4], bfr[4];
    #pragma unroll
    for (int i = 0; i < 4; ++i)
      af[i] = *(const bf16x8*)(ldsc + bi * 8192 +
               (((wr * 64 + i * 16 + ln) * 32 + lg * 8) << 1));
    #pragma unroll
    for (int j = 0; j < 4; ++j)
      bfr[j] = *(const bf16x8*)(ldsc + 16384 + bi * 8192 +
               (((wc * 64 + j * 16 + ln) * 32 + lg * 8) << 1));
    #pragma unroll
    for (int i = 0; i < 4; ++i)
      #pragma unroll
      for (int j = 0; j < 4; ++j)
        acc[i][j] = MFMA16(af[i], bfr[j], acc[i][j]);

    __syncthreads();   // drains prefetch vmcnt; buffer swap safe
  }
  #undef GKVSTAGE

  if (!(by & 1)){
    const int mb = m0 + wr * 64, nb = n0 + wc * 64;
    #pragma unroll
    for (int i = 0; i < 4; ++i)
      #pragma unroll
      for (int j = 0; j < 4; ++j)
        #pragma unroll
        for (int r = 0; r < 4; ++r){
          int mm = mb + i * 16 + lg * 4 + r;
          int nn = nb + j * 16 + ln;
          C[(size_t)mm * N + nn] = f2bf(acc[i][j][r]);
        }
  } else {
    const int h = by >> 1;
    #pragma unroll
    for (int i = 0; i < 4; ++i)
      #pragma unroll
      for (int j = 0; j < 4; ++j){
        int nL = wc * 64 + j * 16 + ln;
        int mL = wr * 64 + i * 16 + lg * 4;
        union { u16 s[4]; unsigned long long u; } pk4;
        #pragma unroll
        for (int r = 0; r < 4; ++r) pk4.s[r] = f2bf(acc[i][j][r]);
        *(unsigned long long*)(ldsc + nL * 256 + ((mL * 2) ^ ((nL & 7) << 4))) = pk4.u;
      }
    __syncthreads();
    const int s0g = bx * 64;
    #pragma unroll
    for (int p = 0; p < 8; ++p){
      int idx = p * 256 + tid;
      int d = idx >> 4, mb8 = idx & 15;
      int m = mb8 * 8;
      us8 v = *(const us8*)(ldsc + d * 256 + ((m * 2) ^ ((d & 7) << 4)));
      union { u16 s[4]; unsigned long long u; } e0, e1;
      e0.s[0] = v[0]; e0.s[1] = v[2]; e0.s[2] = v[4]; e0.s[3] = v[6];
      e1.s[0] = v[1]; e1.s[1] = v[3]; e1.s[2] = v[5]; e1.s[3] = v[7];
      int sg = s0g + (m >> 1);
      *(unsigned long long*)(Vt + ((size_t)(h)      * 128 + d) * 2048 + sg) = e0.u;
      *(unsigned long long*)(Vt + ((size_t)(16 + h) * 128 + d) * 2048 + sg) = e1.u;
    }
  }
}

// ---------- fused RMSNorm, bf16 input (stride 2176) ----------
__global__ __launch_bounds__(256) void k_rms_fused(const u16* __restrict__ in,
                                                   const float* __restrict__ wq,
                                                   const float* __restrict__ wkv,
                                                   u16* __restrict__ outq,
                                                   u16* __restrict__ outkv,
                                                   u16* __restrict__ kpe,
                                                   float* __restrict__ cs_tab){
  __shared__ float red[4];
  const int row = blockIdx.x, tid = threadIdx.x;
  const u16* x = in + (size_t)row * 2176;
  float q8[8];
  const bool hasq = tid < 192;
  float ss = 0.f;
  if (hasq){
    us8 v = *(const us8*)(x + tid * 8);
    #pragma unroll
    for (int j = 0; j < 8; ++j){ q8[j] = bf2f(v[j]); ss += q8[j] * q8[j]; }
  }
  float tot = block_sum256(ss, red, tid);
  float inv = rsqrtf(tot * (1.f / 1536.f) + 1e-6f);
  if (hasq){
    union { u16 s[8]; us8 v; } o;
    #pragma unroll
    for (int j = 0; j < 8; ++j) o.s[j] = f2bf(q8[j] * inv * wq[tid * 8 + j]);
    *(us8*)(outq + (size_t)row * 1536 + tid * 8) = o.v;
  }
  __syncthreads();
  float k8[8];
  const bool haskv = tid < 64;
  float ss2 = 0.f;
  if (haskv){
    us8 v = *(const us8*)(x + 1536 + tid * 8);
    #pragma unroll
    for (int j = 0; j < 8; ++j){ k8[j] = bf2f(v[j]); ss2 += k8[j] * k8[j]; }
  }
  float tot2 = block_sum256(ss2, red, tid);
  float inv2 = rsqrtf(tot2 * (1.f / 512.f) + 1e-6f);
  if (haskv){
    union { u16 s[8]; us8 v; } o;
    #pragma unroll
    for (int j = 0; j < 8; ++j) o.s[j] = f2bf(k8[j] * inv2 * wkv[tid * 8 + j]);
    *(us8*)(outkv + (size_t)row * 512 + tid * 8) = o.v;
  }
  if (tid < 32){
    int j = tid;
    float e = bf2f(x[2048 + 2 * j]), o = bf2f(x[2048 + 2 * j + 1]);
    float pos  = (float)(row >> 1);
    float invf = exp2f(-13.287712379549449f * (float)j * (1.f / 32.f));
    float th = pos * invf, sn = sinf(th), cs = cosf(th);
    kpe[(size_t)row * 64 + j]      = f2bf(e * cs - o * sn);
    kpe[(size_t)row * 64 + 32 + j] = f2bf(o * cs + e * sn);
    cs_tab[(size_t)row * 64 + j]      = cs;
    cs_tab[(size_t)row * 64 + 32 + j] = sn;
  }
}

// ---------- flash attention, causal (R13-proven structure) ----------
__global__ __launch_bounds__(256, 2) void k_attn(const u16* __restrict__ q,
                                                 const u16* __restrict__ kv,
                                                 const u16* __restrict__ kpe,
                                                 const u16* __restrict__ vt,
                                                 const float* __restrict__ cs_tab,
                                                 u16* __restrict__ out){
  const int i_ = blockIdx.x + 16 * (blockIdx.y + 16 * blockIdx.z);
  const int j_ = i_ >> 3, x_ = i_ & 7;
  const int g_ = x_ * 4 + (j_ >> 4);
  const int bx = j_ & 15;
  const int h = g_ & 15, b = g_ >> 4;
  const int bh = b * 16 + h;
  const int tid = threadIdx.x, w = tid >> 6, l = tid & 63;
  const int ln = l & 15, lg = l >> 4;

  __shared__ __align__(16) u16 sK[2][64 * 128];
  __shared__ __align__(16) u16 sPE[2][64 * 64];
  __shared__ __align__(16) u16 sV[2][128 * 64];

  const f32x4 zf = {0.f, 0.f, 0.f, 0.f};

  #define PERM(pr_) ((((pr_) >> 5) << 5) + ((((pr_) >> 2) & 3) << 3) + \
                     ((((pr_) >> 4) & 1) << 2) + ((pr_) & 3))
  #define STAGE(kt_, bi_) {                                                     \
    _Pragma("unroll")                                                           \
    for (int p = 0; p < 4; ++p){                                                \
      int o_ = p * 4096 + tid * 16;                                             \
      int pr = o_ >> 8, cl = (o_ >> 4) & 15, cg = cl ^ (pr & 7);                \
      int kl = PERM(pr);                                                        \
      gload16(kv + (size_t)(((kt_) * 64 + kl) * 2 + b) * 4096 + h * 256 + cg * 8, \
              (char*)sK[bi_] + o_);                                             \
    }                                                                           \
    _Pragma("unroll")                                                           \
    for (int p = 0; p < 2; ++p){                                                \
      int o_ = p * 4096 + tid * 16;                                             \
      int pr = o_ >> 7, cl = (o_ >> 4) & 7, cg = cl ^ (pr & 7);                 \
      int kl = PERM(pr);                                                        \
      gload16(kpe + (size_t)(((kt_) * 64 + kl) * 2 + b) * 64 + cg * 8,          \
              (char*)sPE[bi_] + o_);                                            \
    }                                                                           \
    _Pragma("unroll")                                                           \
    for (int p = 0; p < 4; ++p){                                                \
      int o_ = p * 4096 + tid * 16;                                             \
      int row = o_ >> 7, cl = (o_ >> 4) & 7, cg = cl ^ (row & 7);               \
      gload16(vt + (size_t)(bh * 128 + row) * 2048 + (kt_) * 64 + cg * 8,       \
              (char*)sV[bi_] + o_);                                             \
    } }

  for (int half = 0; half < 2; ++half){
    const int qt = half ? (31 - bx) : bx;
    const int qrow0 = qt * 64 + w * 16;
    const int sq = qrow0 + ln;

    bf16x8 qf[6];
    {
      const u16* qr = q + (size_t)(sq * 2 + b) * 3072 + h * 192;
      #pragma unroll
      for (int kb = 0; kb < 4; ++kb) qf[kb] = *(const bf16x8*)(qr + kb * 32 + lg * 8);
      u16 rawa[16];
      *(us8*)&rawa[0] = *(const us8*)(qr + 128 + 16 * lg);
      *(us8*)&rawa[8] = *(const us8*)(qr + 128 + 16 * lg + 8);
      const float* ct = cs_tab + (size_t)(sq * 2 + b) * 64 + 8 * lg;
      float cc[8], ss_[8];
      *(float4*)&cc[0]  = *(const float4*)(ct);
      *(float4*)&cc[4]  = *(const float4*)(ct + 4);
      *(float4*)&ss_[0] = *(const float4*)(ct + 32);
      *(float4*)&ss_[4] = *(const float4*)(ct + 36);
      union { u16 s[8]; bf16x8 v; } pe4, pe5;
      #pragma unroll
      for (int i2 = 0; i2 < 8; ++i2){
        float e  = bf2f(rawa[2 * i2]);
        float o2 = bf2f(rawa[2 * i2 + 1]);
        pe4.s[i2] = f2bf(e * cc[i2] - o2 * ss_[i2]);
        pe5.s[i2] = f2bf(o2 * cc[i2] + e * ss_[i2]);
      }
      qf[4] = pe4.v;
      qf[5] = pe5.v;
    }

    f32x4 o[8];
    float m_i = -3.0e38f, l_i = 0.f;
    #pragma unroll
    for (int c8 = 0; c8 < 8; ++c8) o[c8] = zf;

    const int nkt = qt + 1;
    STAGE(0, 0);
    __syncthreads();

    for (int kt = 0; kt < nkt; ++kt){
      const int bi = kt & 1;
      if (kt + 1 < nkt) STAGE(kt + 1, bi ^ 1);

      f32x4 s_[4];
      #pragma unroll
      for (int cb = 0; cb < 4; ++cb){
        int rl = cb * 16 + ln, swz = rl & 7;
        bf16x8 kf[6];
        #pragma unroll
        for (int kb = 0; kb < 4; ++kb)
          kf[kb] = *(const bf16x8*)((char*)sK[bi] + rl * 256 + (((kb * 4 + lg) ^ swz) << 4));
        kf[4] = *(const bf16x8*)((char*)sPE[bi] + rl * 128 + ((lg ^ swz) << 4));
        kf[5] = *(const bf16x8*)((char*)sPE[bi] + rl * 128 + (((4 + lg) ^ swz) << 4));
        f32x4 acc = zf;
        #pragma unroll
        for (int kb = 0; kb < 6; ++kb)
          acc = MFMA16(kf[kb], qf[kb], acc);
        s_[cb] = acc;
      }

      const bool needMask = (kt * 64 + 63) > qrow0;
      float mx = -3.0e38f;
      #pragma unroll
      for (int cb = 0; cb < 4; ++cb)
        #pragma unroll
        for (int r = 0; r < 4; ++r){
          float v = s_[cb][r];
          if (needMask){
            int sk = kt * 64 + 32 * (cb >> 1) + 8 * lg + 4 * (cb & 1) + r;
            v = (sk <= sq) ? v : -3.0e38f;
          }
          s_[cb][r] = v;
          mx = fmaxf(mx, v);
        }
      mx = fmaxf(mx, __shfl_xor(mx, 16));
      mx = fmaxf(mx, __shfl_xor(mx, 32));
      if (!__all(mx <= m_i + 11.6f)){
        float mn = fmaxf(m_i, mx);
        float sf = exp2f(m_i - mn);
        m_i = mn;
        l_i *= sf;
        float sf0 = __shfl(sf, 4 * lg + 0);
        float sf1 = __shfl(sf, 4 * lg + 1);
        float sf2 = __shfl(sf, 4 * lg + 2);
        float sf3 = __shfl(sf, 4 * lg + 3);
        #pragma unroll
        for (int c8 = 0; c8 < 8; ++c8){
          o[c8][0] *= sf0; o[c8][1] *= sf1; o[c8][2] *= sf2; o[c8][3] *= sf3;
        }
      }
      float rs = 0.f;
      #pragma unroll
      for (int cb = 0; cb < 4; ++cb)
        #pragma unroll
        for (int r = 0; r < 4; ++r){
          float p = exp2f(s_[cb][r] - m_i);
          s_[cb][r] = p;
          rs += p;
        }
      rs += __shfl_xor(rs, 16);
      rs += __shfl_xor(rs, 32);
      l_i += rs;

      bf16x8 pa[2];
      #pragma unroll
      for (int hf = 0; hf < 2; ++hf){
        unsigned pw0, pw1, pw2, pw3;
        f32x4 sa = s_[hf * 2], sb2 = s_[hf * 2 + 1];
        asm("v_cvt_pk_bf16_f32 %0, %1, %2" : "=v"(pw0) : "v"(sa[0]),  "v"(sa[1]));
        asm("v_cvt_pk_bf16_f32 %0, %1, %2" : "=v"(pw1) : "v"(sa[2]),  "v"(sa[3]));
        asm("v_cvt_pk_bf16_f32 %0, %1, %2" : "=v"(pw2) : "v"(sb2[0]), "v"(sb2[1]));
        asm("v_cvt_pk_bf16_f32 %0, %1, %2" : "=v"(pw3) : "v"(sb2[2]), "v"(sb2[3]));
        union { uint4 u; bf16x8 v; } pk;
        pk.u.x = pw0; pk.u.y = pw1; pk.u.z = pw2; pk.u.w = pw3;
        pa[hf] = pk.v;
      }

      #pragma unroll
      for (int c8 = 0; c8 < 8; ++c8){
        int d = c8 * 16 + ln, swz = d & 7;
        bf16x8 vf0 = *(const bf16x8*)((char*)sV[bi] + d * 128 + ((lg ^ swz) << 4));
        bf16x8 vf1 = *(const bf16x8*)((char*)sV[bi] + d * 128 + (((4 + lg) ^ swz) << 4));
        o[c8] = MFMA16(pa[0], vf0, o[c8]);
        o[c8] = MFMA16(pa[1], vf1, o[c8]);
      }
      __syncthreads();
    }

    float li0 = __shfl(l_i, 4 * lg + 0);
    float li1 = __shfl(l_i, 4 * lg + 1);
    float li2 = __shfl(l_i, 4 * lg + 2);
    float li3 = __shfl(l_i, 4 * lg + 3);
    float iv0 = 1.f / li0, iv1 = 1.f / li1, iv2 = 1.f / li2, iv3 = 1.f / li3;
    int sqr = qrow0 + lg * 4;
    #pragma unroll
    for (int c8 = 0; c8 < 8; ++c8){
      int col = h * 128 + c8 * 16 + ln;
      out[(size_t)((sqr + 0) * 2 + b) * 2048 + col] = f2bf(o[c8][0] * iv0);
      out[(size_t)((sqr + 1) * 2 + b) * 2048 + col] = f2bf(o[c8][1] * iv1);
      out[(size_t)((sqr + 2) * 2 + b) * 2048 + col] = f2bf(o[c8][2] * iv2);
      out[(size_t)((sqr + 3) * 2 + b) * 2048 + col] = f2bf(o[c8][3] * iv3);
    }
  }
  #undef STAGE
  #undef PERM
}

// ---------- launch ----------
extern "C" void kernel_launch(void* const* d_in, const int* in_sizes, int n_in,
                              void* d_out, int out_size, void* d_ws, size_t ws_size,
                              hipStream_t stream){
  const float* hidden    = (const float*)d_in[0];
  const float* wq_a      = (const float*)d_in[3];
  const float* q_a_ln_w  = (const float*)d_in[4];
  const float* wq_b      = (const float*)d_in[5];
  const float* wkv_a     = (const float*)d_in[6];
  const float* kv_a_ln_w = (const float*)d_in[7];
  const float* wkv_b     = (const float*)d_in[8];
  const float* wo        = (const float*)d_in[9];

  char* ws = (char*)d_ws;
  size_t off = 0;
  auto alloc = [&](size_t bytes){ size_t o = off; off += (bytes + 255) & ~(size_t)255; return o; };
  const size_t SB = 4096;

  u16*   hid_bf   = (u16*)(ws + alloc(SB * 2048 * 2));
  u16*   wqab_bf  = (u16*)(ws + alloc((size_t)2176 * 2048 * 2));
  u16*   wqb_bf   = (u16*)(ws + alloc((size_t)3072 * 1536 * 2));
  u16*   wkvb_bf  = (u16*)(ws + alloc((size_t)4096 * 512 * 2));
  u16*   wo_bf    = (u16*)(ws + alloc((size_t)2048 * 2048 * 2));
  u16*   qa_bf    = (u16*)(ws + alloc(SB * 2176 * 2));   // merged q_a | ckv (bf16)
  u16*   qrms_bf  = (u16*)(ws + alloc(SB * 1536 * 2));
  u16*   ckvr_bf  = (u16*)(ws + alloc(SB * 512 * 2));
  u16*   kpe_bf   = (u16*)(ws + alloc(SB * 64 * 2));
  float* cs_f     = (float*)(ws + alloc(SB * 64 * 4));
  u16*   qfull_bf = (u16*)(ws + alloc(SB * 3072 * 2));
  u16*   kv_bf    = (u16*)(ws + alloc(SB * 4096 * 2));
  u16*   attn_bf  = (u16*)(ws + alloc(SB * 2048 * 2));
  u16*   vt_bf    = hid_bf;        // alias: hidden_bf16 dead after merged GEMM1

  dim3 blk(256);
  k_convall<<<2048, blk, 0, stream>>>(hidden, wq_a, wq_b, wkv_b, wo, wkv_a,
                                      hid_bf, wqab_bf, wqb_bf, wkvb_bf, wo_bf,
                                      wqab_bf + (size_t)1536 * 2048);
  k_gemm<1><<<dim3(32, 17), blk, 0, stream>>>(hid_bf, wqab_bf, qa_bf, 4096, 2176, 2048);
  k_rms_fused<<<4096, blk, 0, stream>>>(qa_bf, q_a_ln_w, kv_a_ln_w, qrms_bf, ckvr_bf,
                                        kpe_bf, cs_f);
  k_gemm<1><<<dim3(32, 24), blk, 0, stream>>>(qrms_bf, wqb_bf, qfull_bf, 4096, 3072, 1536);
  k_gemm_kv<<<dim3(32, 32), blk, 0, stream>>>(ckvr_bf, wkvb_bf, kv_bf, vt_bf);
  k_attn<<<dim3(16, 16, 2), blk, 0, stream>>>(qfull_bf, kv_bf, kpe_bf, vt_bf, cs_f, attn_bf);
  k_gemm<0><<<dim3(32, 16), blk, 0, stream>>>(attn_bf, wo_bf, d_out, 4096, 2048, 2048);
}